// Round 5
// baseline (1229.761 us; speedup 1.0000x reference)
//
#include <hip/hip_runtime.h>
#include <math.h>

#define NB 8192
#define ND 256
#define MARGIN_F 0.3f
#define EPS_F 1e-6f
#define BIAS_F 512.0f          // v = |e_j|^2 + BIAS - 2*dot stays strictly positive
#define NFIN 2048              // finalize grid
#define NEG_INIT 0x7F800000u   // +inf bits: neg-side sentinel (all real keys finite, positive)

typedef __attribute__((ext_vector_type(8))) short bf16x8;
typedef __attribute__((ext_vector_type(4))) float f32x4;

__device__ __forceinline__ unsigned short f2bf(float x) {
    unsigned int u = __float_as_uint(x);
    return (unsigned short)((u + 0x7fffu + ((u >> 16) & 1u)) >> 16);
}

__device__ __forceinline__ void gld16(const void* g, void* l) {
    __builtin_amdgcn_global_load_lds(
        (const __attribute__((address_space(1))) void*)g,
        (__attribute__((address_space(3))) void*)l, 16, 0, 0);
}

// ---- prep: fp32 -> bf16 packed in MFMA-fragment order, + biased sq norms, + key/ticket init
// Packed layout: row-group g=(row>>4): 8 subtiles (k>>5); within: lane=((k>>3)&3)*16+(row&15), 8 bf16.
__global__ __launch_bounds__(512) void prep_k(const float* __restrict__ emb,
                                              unsigned short* __restrict__ ehi,
                                              float* __restrict__ sqnb,
                                              unsigned int* __restrict__ pos_key,
                                              unsigned int* __restrict__ neg_key,
                                              unsigned int* __restrict__ ticket) {
    __shared__ float sm[8][16];
    const int tid = threadIdx.x;
    const int tk = tid >> 6;          // k-tile 0..7
    const int lane = tid & 63;
    const int q = lane >> 4;
    const int lx = lane & 15;
    const int row = blockIdx.x * 16 + lx;
    const int k = tk * 32 + q * 8;

    const float4 v0 = *reinterpret_cast<const float4*>(&emb[(size_t)row * ND + k]);
    const float4 v1 = *reinterpret_cast<const float4*>(&emb[(size_t)row * ND + k + 4]);
    ushort4 h0, h1;
    h0.x = f2bf(v0.x); h0.y = f2bf(v0.y); h0.z = f2bf(v0.z); h0.w = f2bf(v0.w);
    h1.x = f2bf(v1.x); h1.y = f2bf(v1.y); h1.z = f2bf(v1.z); h1.w = f2bf(v1.w);
    *reinterpret_cast<ushort4*>(&ehi[(size_t)blockIdx.x * 4096 + tid * 8])     = h0;
    *reinterpret_cast<ushort4*>(&ehi[(size_t)blockIdx.x * 4096 + tid * 8 + 4]) = h1;

    if (tid >= 32 && tid < 48) pos_key[blockIdx.x * 16 + (tid - 32)] = 0u;
    if (tid >= 48 && tid < 64) neg_key[blockIdx.x * 16 + (tid - 48)] = NEG_INIT;
    if (blockIdx.x == 0 && tid == 0) atomicExch(ticket, 0u);

    float s = v0.x * v0.x + v0.y * v0.y + v0.z * v0.z + v0.w * v0.w
            + v1.x * v1.x + v1.y * v1.y + v1.z * v1.z + v1.w * v1.w;
    s += __shfl_xor(s, 16, 64);
    s += __shfl_xor(s, 32, 64);
    if (q == 0) sm[tk][lx] = s;
    __syncthreads();
    if (tid < 16) {
        float t = 0.0f;
#pragma unroll
        for (int wv = 0; wv < 8; ++wv) t += sm[wv][tid];
        sqnb[blockIdx.x * 16 + tid] = t + BIAS_F;
    }
}

// ---- mining: v = sqj + BIAS - 2*dot via fmaf; keys as positive floats (max3/min3-fusable).
//      Row labels re-read from LDS as int4 (keeps them out of long-lived registers).
template <bool DIAG>
__device__ __forceinline__ void mine_jt(
        const f32x4 (&acc)[4][4], const int* __restrict__ lbl_j_s,
        const float* __restrict__ sqj_s, const int* __restrict__ lbl_i_s,
        float (&pmax)[16], float (&nmin)[16],
        int jt, int jcol0, int wr_base, int w, int q, int lx) {
    const float NEGF = __uint_as_float(NEG_INIT);
#pragma unroll
    for (int tr = 0; tr < 4; ++tr) {
        const int4 lab4 = *reinterpret_cast<const int4*>(&lbl_i_s[w * 64 + tr * 16 + q * 4]);
        const int labs[4] = {lab4.x, lab4.y, lab4.z, lab4.w};
#pragma unroll
        for (int tc = 0; tc < 4; ++tc) {
            const int jcl = jt * 64 + tc * 16 + lx;
            const int lblj = lbl_j_s[jcl];
            const float sj = sqj_s[jcl];
            const int colg = jcol0 + jcl;
            const unsigned encv = 8191u - (unsigned)colg;
#pragma unroll
            for (int reg = 0; reg < 4; ++reg) {
                const int r = tr * 4 + reg;
                const float v = fmaf(-2.0f, acc[tr][tc][reg], sj);
                const float keyf = __uint_as_float(
                    (__float_as_uint(v) & 0xFFFFE000u) | encv);
                const bool same = (lblj == labs[reg]);
                bool pc = same;
                if (DIAG) pc = same && (colg != (wr_base + tr * 16 + q * 4 + reg));
                pmax[r] = fmaxf(pmax[r], pc ? keyf : 0.0f);
                nmin[r] = fminf(nmin[r], same ? NEGF : keyf);
            }
        }
    }
}

// ---- MFMA pairwise + hardest mining, v6:
//      Block tile 256 rows x 256 cols; 4 waves; wave = 64 rows x 256 cols.
//      A transient from L2-hot packed ehi (16 VGPR live); acc[4][4] (64 regs);
//      B: 64-col x 128-k chunks (16 KB) double-buffered via global_load_lds,
//      staged one phase ahead; 2 barriers per 64-col j-step.
//      Each ds_read_b128 B-fragment feeds 4 MFMAs -> 2 MB/CU LDS read traffic.
//      LDS 35 KB + VGPR<=128 -> 4 blocks/CU (16 waves) for cross-wave pipe overlap.
//      grid 1024 = 32 i-tiles x 32 slices = exactly 4 blocks/CU, no tail.
__global__ __launch_bounds__(256, 4) void pair_k(
        const unsigned short* __restrict__ ehi, const float* __restrict__ sqnb,
        const int* __restrict__ labels,
        unsigned int* __restrict__ pos_key, unsigned int* __restrict__ neg_key) {
    __shared__ __align__(16) short Bsh[2][8192];       // 2 x 16 KB
    __shared__ __align__(16) int lbl_i_s[256];
    __shared__ __align__(16) int lbl_j_s[256];
    __shared__ __align__(16) float sqj_s[256];

    const int tid = threadIdx.x;
    const int w = tid >> 6, lane = tid & 63, q = lane >> 4, lx = lane & 15;
    const int bid = blockIdx.x;
    const int slice = bid & 31;
    const int i_base = (bid >> 5) * 256;
    const int jcol0 = slice * 256;
    const int wr_base = i_base + w * 64;
    const int ga0 = wr_base >> 4;                      // wave's 4 A row-groups

    lbl_i_s[tid] = labels[i_base + tid];
    lbl_j_s[tid] = labels[jcol0 + tid];
    sqj_s[tid]   = sqnb[jcol0 + tid];

// stage chunk (j-step JT, k-half KH) -> Bsh[BUF]: 16 KB, 4 gld16/thread.
// p selects the col-group; within it the 4 k-subtiles of half KH are contiguous in ehi.
#define STAGE(JT, KH, BUF)                                                           \
    do {                                                                             \
        _Pragma("unroll")                                                            \
        for (int p = 0; p < 4; ++p)                                                  \
            gld16(ehi + ((size_t)((slice * 16 + (JT) * 4 + p) * 8 + (KH) * 4)) * 512 \
                      + tid * 8,                                                     \
                  &Bsh[BUF][(p * 256 + tid) * 8]);                                   \
    } while (0)

// 64 MFMAs on Bsh[BUF] (k-half KH): A frags streamed from L2-hot ehi, 16B each
#define PHASE(BUF, KH)                                                               \
    do {                                                                             \
        __builtin_amdgcn_s_setprio(1);                                               \
        _Pragma("unroll")                                                            \
        for (int kb = 0; kb < 4; ++kb) {                                             \
            bf16x8 ac[4];                                                            \
            _Pragma("unroll")                                                        \
            for (int tr = 0; tr < 4; ++tr)                                           \
                ac[tr] = *reinterpret_cast<const bf16x8*>(                           \
                    &ehi[((size_t)(ga0 + tr) * 8 + (KH) * 4 + kb) * 512 + lane * 8]); \
            _Pragma("unroll")                                                        \
            for (int tc = 0; tc < 4; ++tc) {                                         \
                const bf16x8 bh = *reinterpret_cast<const bf16x8*>(                  \
                    &Bsh[BUF][(tc * 4 + kb) * 512 + lane * 8]);                      \
                _Pragma("unroll")                                                    \
                for (int tr = 0; tr < 4; ++tr)                                       \
                    acc[tr][tc] = __builtin_amdgcn_mfma_f32_16x16x32_bf16(           \
                        ac[tr], bh, acc[tr][tc], 0, 0, 0);                           \
            }                                                                        \
        }                                                                            \
        __builtin_amdgcn_s_setprio(0);                                               \
    } while (0)

    STAGE(0, 0, 0);   // prologue stage; drained by the barrier below

    float pmax[16], nmin[16];
    const float NEGF = __uint_as_float(NEG_INIT);
#pragma unroll
    for (int r = 0; r < 16; ++r) { pmax[r] = 0.0f; nmin[r] = NEGF; }

    __syncthreads();   // prologue gld16 drained; metadata LDS visible

#pragma unroll 1
    for (int jt = 0; jt < 4; ++jt) {
        STAGE(jt, 1, 1);                               // issue k-half 1; hidden under MFMAs

        f32x4 acc[4][4];
#pragma unroll
        for (int tr = 0; tr < 4; ++tr)
#pragma unroll
            for (int tc = 0; tc < 4; ++tc) acc[tr][tc] = (f32x4){0.f, 0.f, 0.f, 0.f};

        PHASE(0, 0);
        __syncthreads();                               // buf1 staged+visible; buf0 consumed
        if (jt < 3) STAGE(jt + 1, 0, 0);               // issue next j-step's k-half 0
        PHASE(1, 1);

        if (jcol0 + jt * 64 == wr_base)
            mine_jt<true >(acc, lbl_j_s, sqj_s, lbl_i_s, pmax, nmin,
                           jt, jcol0, wr_base, w, q, lx);
        else
            mine_jt<false>(acc, lbl_j_s, sqj_s, lbl_i_s, pmax, nmin,
                           jt, jcol0, wr_base, w, q, lx);

        __syncthreads();                               // buf0 staged+visible; buf1 consumed
    }
#undef STAGE
#undef PHASE

    // once-per-kernel cross-lane reduce (16-lane groups) + spread-address atomics
#pragma unroll
    for (int r = 0; r < 16; ++r) {
        float pm = pmax[r], nm = nmin[r];
#pragma unroll
        for (int mm = 1; mm < 16; mm <<= 1) {
            pm = fmaxf(pm, __shfl_xor(pm, mm, 64));
            nm = fminf(nm, __shfl_xor(nm, mm, 64));
        }
        if (lx == r) {
            const int row = wr_base + (r >> 2) * 16 + q * 4 + (r & 3);
            atomicMax(&pos_key[row], __float_as_uint(pm));
            atomicMin(&neg_key[row], __float_as_uint(nm));
        }
    }
}

// ---- finalize: decode keys, exact fp32 gather, hinge, per-block partials; the ticket's
//      last block performs the (order-identical) final reduction in-kernel.
__global__ __launch_bounds__(256) void final_k(
        const float* __restrict__ emb,
        const unsigned int* __restrict__ pos_key, const unsigned int* __restrict__ neg_key,
        float* __restrict__ pbsum, float* __restrict__ pbcnt,
        unsigned int* __restrict__ ticket, float* __restrict__ out) {
    __shared__ float ssum[4], scnt[4];
    __shared__ float fs[4], fc[4];
    __shared__ unsigned int lastf;
    const int tid = threadIdx.x;
    const int w = tid >> 6;
    const int lane = tid & 63;
    const int i = blockIdx.x * 4 + w;

    const unsigned pk = pos_key[i], nk = neg_key[i];
    const int pi = 8191 - (int)(pk & 8191u);
    const int ni = 8191 - (int)(nk & 8191u);
    const bool valid = (pk != 0u) && (nk != NEG_INIT);

    const float4 av  = *reinterpret_cast<const float4*>(&emb[(size_t)i  * ND + lane * 4]);
    const float4 pvv = *reinterpret_cast<const float4*>(&emb[(size_t)pi * ND + lane * 4]);
    const float4 nvv = *reinterpret_cast<const float4*>(&emb[(size_t)ni * ND + lane * 4]);
    float sap, san;
    {
        const float d0 = av.x - pvv.x + EPS_F, d1 = av.y - pvv.y + EPS_F;
        const float d2 = av.z - pvv.z + EPS_F, d3 = av.w - pvv.w + EPS_F;
        sap = d0 * d0 + d1 * d1 + d2 * d2 + d3 * d3;
        const float e0 = av.x - nvv.x + EPS_F, e1 = av.y - nvv.y + EPS_F;
        const float e2 = av.z - nvv.z + EPS_F, e3 = av.w - nvv.w + EPS_F;
        san = e0 * e0 + e1 * e1 + e2 * e2 + e3 * e3;
    }
#pragma unroll
    for (int m = 32; m; m >>= 1) {
        sap += __shfl_down(sap, m, 64);
        san += __shfl_down(san, m, 64);
    }
    if (lane == 0) {
        const float per = fmaxf(sqrtf(sap) - sqrtf(san) + MARGIN_F, 0.0f);
        ssum[w] = valid ? per : 0.0f;
        scnt[w] = valid ? 1.0f : 0.0f;
    }
    __syncthreads();
    if (tid == 0) {
        pbsum[blockIdx.x] = ssum[0] + ssum[1] + ssum[2] + ssum[3];
        pbcnt[blockIdx.x] = scnt[0] + scnt[1] + scnt[2] + scnt[3];
        __threadfence();                               // partials visible device-wide
        lastf = (atomicAdd(ticket, 1u) == (unsigned)(NFIN - 1)) ? 1u : 0u;
    }
    __syncthreads();
    if (lastf != 0u) {                                 // uniform per block
        float s = 0.0f, c = 0.0f;
#pragma unroll
        for (int r = 0; r < NFIN / 256; ++r) {         // atomic-RMW reads: device-coherent
            s += atomicAdd(&pbsum[r * 256 + tid], 0.0f);
            c += atomicAdd(&pbcnt[r * 256 + tid], 0.0f);
        }
#pragma unroll
        for (int m = 32; m; m >>= 1) { s += __shfl_down(s, m, 64); c += __shfl_down(c, m, 64); }
        if (lane == 0) { fs[w] = s; fc[w] = c; }
        __syncthreads();
        if (tid == 0) {
            const float S = fs[0] + fs[1] + fs[2] + fs[3];
            const float C = fc[0] + fc[1] + fc[2] + fc[3];
            out[0] = (C > 0.0f) ? (S / fmaxf(C, 1.0f)) : 0.0f;
        }
    }
}

extern "C" void kernel_launch(void* const* d_in, const int* in_sizes, int n_in,
                              void* d_out, int out_size, void* d_ws, size_t ws_size,
                              hipStream_t stream) {
    const float* emb = (const float*)d_in[0];
    const int* labels = (const int*)d_in[1];
    float* out = (float*)d_out;

    char* ws = (char*)d_ws;
    unsigned short* ehi = (unsigned short*)ws;                         // 4 MB packed
    float* sqnb = (float*)(ws + (size_t)NB * ND * 2);                  // 32 KB
    unsigned int* pos_key = (unsigned int*)(sqnb + NB);                // 32 KB
    unsigned int* neg_key = pos_key + NB;                              // 32 KB
    float* pbsum = (float*)(neg_key + NB);                             // 8 KB
    float* pbcnt = pbsum + NFIN;                                       // 8 KB
    unsigned int* ticket = (unsigned int*)(pbcnt + NFIN);              // 4 B

    hipLaunchKernelGGL(prep_k, dim3(NB / 16), dim3(512), 0, stream,
                       emb, ehi, sqnb, pos_key, neg_key, ticket);
    hipLaunchKernelGGL(pair_k, dim3(1024), dim3(256), 0, stream,
                       ehi, sqnb, labels, pos_key, neg_key);
    hipLaunchKernelGGL(final_k, dim3(NFIN), dim3(256), 0, stream,
                       emb, pos_key, neg_key, pbsum, pbcnt, ticket, out);
}

// Round 6
// 158.755 us; speedup vs baseline: 7.7463x; 7.7463x over previous
//
#include <hip/hip_runtime.h>
#include <math.h>

#define NB 8192
#define ND 256
#define MARGIN_F 0.3f
#define EPS_F 1e-6f
#define BIAS_F 512.0f          // v = |e_j|^2 + BIAS - 2*dot stays strictly positive
#define NFIN 2048              // finalize grid

typedef __attribute__((ext_vector_type(8))) short bf16x8;
typedef __attribute__((ext_vector_type(4))) float f32x4;

__device__ __forceinline__ unsigned short f2bf(float x) {
    unsigned int u = __float_as_uint(x);
    return (unsigned short)((u + 0x7fffu + ((u >> 16) & 1u)) >> 16);
}

__device__ __forceinline__ void gld16(const void* g, void* l) {
    __builtin_amdgcn_global_load_lds(
        (const __attribute__((address_space(1))) void*)g,
        (__attribute__((address_space(3))) void*)l, 16, 0, 0);
}

// ---- prep: fp32 -> bf16 packed in MFMA-fragment order, + biased sq norms, + key/ticket init
// Packed layout: subtile = (row>>4)*8 + (k>>5); within: lane = ((k>>3)&3)*16 + (row&15), 8 bf16.
__global__ __launch_bounds__(512) void prep_k(const float* __restrict__ emb,
                                              unsigned short* __restrict__ ehi,
                                              float* __restrict__ sqnb,
                                              unsigned int* __restrict__ pos_key,
                                              unsigned int* __restrict__ neg_key,
                                              unsigned int* __restrict__ ticket) {
    __shared__ float sm[8][16];
    const int tid = threadIdx.x;
    const int tk = tid >> 6;          // k-tile 0..7
    const int lane = tid & 63;
    const int q = lane >> 4;
    const int lx = lane & 15;
    const int row = blockIdx.x * 16 + lx;
    const int k = tk * 32 + q * 8;

    const float4 v0 = *reinterpret_cast<const float4*>(&emb[(size_t)row * ND + k]);
    const float4 v1 = *reinterpret_cast<const float4*>(&emb[(size_t)row * ND + k + 4]);
    ushort4 h0, h1;
    h0.x = f2bf(v0.x); h0.y = f2bf(v0.y); h0.z = f2bf(v0.z); h0.w = f2bf(v0.w);
    h1.x = f2bf(v1.x); h1.y = f2bf(v1.y); h1.z = f2bf(v1.z); h1.w = f2bf(v1.w);
    *reinterpret_cast<ushort4*>(&ehi[(size_t)blockIdx.x * 4096 + tid * 8])     = h0;
    *reinterpret_cast<ushort4*>(&ehi[(size_t)blockIdx.x * 4096 + tid * 8 + 4]) = h1;

    if (tid >= 32 && tid < 48) pos_key[blockIdx.x * 16 + (tid - 32)] = 0u;
    if (tid >= 48 && tid < 64) neg_key[blockIdx.x * 16 + (tid - 48)] = 0xFFFFFFFFu;
    if (blockIdx.x == 0 && tid == 0) atomicExch(ticket, 0u);

    float s = v0.x * v0.x + v0.y * v0.y + v0.z * v0.z + v0.w * v0.w
            + v1.x * v1.x + v1.y * v1.y + v1.z * v1.z + v1.w * v1.w;
    s += __shfl_xor(s, 16, 64);
    s += __shfl_xor(s, 32, 64);
    if (q == 0) sm[tk][lx] = s;
    __syncthreads();
    if (tid < 16) {
        float t = 0.0f;
#pragma unroll
        for (int wv = 0; wv < 8; ++wv) t += sm[wv][tid];
        sqnb[blockIdx.x * 16 + tid] = t + BIAS_F;
    }
}

// ---- mining epilogue: tree-max reduction, ~7 VALU / element ----
template <bool DIAG>
__device__ __forceinline__ void mine_tile(
        const f32x4 (&acc)[2][4], const float (&sqjc)[4], const int (&lblc)[4],
        const unsigned (&enc)[4], const int* __restrict__ lbl_i_s,
        unsigned (&pmax)[8], unsigned (&nmin)[8],
        int i_base, int jb, int wrow, int q, int lx) {
#pragma unroll
    for (int tr = 0; tr < 2; ++tr) {
#pragma unroll
        for (int reg = 0; reg < 4; ++reg) {
            const int r = tr * 4 + reg;
            const int rowb = wrow + tr * 16 + q * 4 + reg;
            const int lab = lbl_i_s[rowb];
            unsigned pk[4], nk[4];
#pragma unroll
            for (int tc = 0; tc < 4; ++tc) {
                const float v = fmaf(-2.0f, acc[tr][tc][reg], sqjc[tc]);
                const unsigned key = (__float_as_uint(v) & 0xFFFFE000u) | enc[tc];
                const bool same = (lblc[tc] == lab);
                bool pc = same;
                if (DIAG) pc = same && ((jb + tc * 16 + lx) != (i_base + rowb));
                pk[tc] = pc ? key : 0u;
                nk[tc] = same ? 0xFFFFFFFFu : key;
            }
            const unsigned pa = pk[0] >= pk[1] ? pk[0] : pk[1];
            const unsigned pb = pk[2] >= pk[3] ? pk[2] : pk[3];
            const unsigned pm = pa >= pb ? pa : pb;
            pmax[r] = pmax[r] >= pm ? pmax[r] : pm;
            const unsigned na = nk[0] <= nk[1] ? nk[0] : nk[1];
            const unsigned nb = nk[2] <= nk[3] ? nk[2] : nk[3];
            const unsigned nm = na <= nb ? na : nb;
            nmin[r] = nmin[r] <= nm ? nmin[r] : nm;
        }
    }
}

// ---- MFMA pairwise + hardest mining: 128x64 j-steps, B-step (32 KB) in LDS,
//      A frags transient from global (double-buffered). grid 1024 -> 4 blocks/CU.
//      slice = bid&15 (512 cols), i_tile = bid>>4. block 256 = 4 waves;
//      wave w: rows w*32..w*32+31, all 64 cols.
__global__ __launch_bounds__(256, 4) void pair_k(
        const unsigned short* __restrict__ ehi, const float* __restrict__ sqnb,
        const int* __restrict__ labels,
        unsigned int* __restrict__ pos_key, unsigned int* __restrict__ neg_key) {
    __shared__ short Bsh[32 * 512];  // B j-step: 64 cols x 256 k = 16384 shorts = 32 KB
    __shared__ int   lbl_i_s[128];

    const int tid = threadIdx.x;
    const int w = tid >> 6;
    const int lane = tid & 63;
    const int q = lane >> 4;
    const int lx = lane & 15;
    const int bid = blockIdx.x;
    const int slice = bid & 15;
    const int i_base = (bid >> 4) * 128;
    const int wrow = w * 32;
    const int g0 = (i_base >> 4) + w * 2;   // A row-group base for this wave (2 subtiles)

    if (tid < 128) lbl_i_s[tid] = labels[i_base + tid];

    unsigned pmax[8], nmin[8];
#pragma unroll
    for (int r = 0; r < 8; ++r) { pmax[r] = 0u; nmin[r] = 0xFFFFFFFFu; }

#pragma unroll 1
    for (int jt = 0; jt < 8; ++jt) {
        const int jb = slice * 512 + jt * 64;
        __syncthreads();   // prev j-step's Bsh reads complete
        // stage B j-step: contiguous 32 KB of packed ehi (8 gld16/thread)
        {
            const unsigned short* srcB = ehi + (size_t)(jb >> 4) * 4096;
#pragma unroll
            for (int p = 0; p < 8; ++p)
                gld16(srcB + ((size_t)p * 256 + tid) * 8, Bsh + (p * 256 + tid) * 8);
        }
        // j-step metadata + first A frags issued before the drain barrier
        int lblc[4]; float sqjc[4]; unsigned enc[4];
#pragma unroll
        for (int tc = 0; tc < 4; ++tc) {
            const int jj = jb + tc * 16 + lx;
            lblc[tc] = labels[jj];
            sqjc[tc] = sqnb[jj];
            enc[tc] = 8191u - (unsigned)jj;
        }
        bf16x8 a0[2], a1[2];
#pragma unroll
        for (int tr = 0; tr < 2; ++tr)
            a0[tr] = *(const bf16x8*)&ehi[((size_t)(g0 + tr) * 8 + 0) * 512 + lane * 8];
        __syncthreads();   // gld16 drained; Bsh visible

        f32x4 acc[2][4];
#pragma unroll
        for (int a = 0; a < 2; ++a)
#pragma unroll
            for (int b = 0; b < 4; ++b) acc[a][b] = (f32x4){0.f, 0.f, 0.f, 0.f};

#pragma unroll 1
        for (int kb2 = 0; kb2 < 4; ++kb2) {
            const int kbe = kb2 * 2, kbo = kbe + 1;
#pragma unroll
            for (int tr = 0; tr < 2; ++tr)
                a1[tr] = *(const bf16x8*)&ehi[((size_t)(g0 + tr) * 8 + kbo) * 512 + lane * 8];
            {
                bf16x8 bh[4];
#pragma unroll
                for (int tc = 0; tc < 4; ++tc)
                    bh[tc] = *(const bf16x8*)&Bsh[(tc * 8 + kbe) * 512 + lane * 8];
#pragma unroll
                for (int tr = 0; tr < 2; ++tr)
#pragma unroll
                    for (int tc = 0; tc < 4; ++tc)
                        acc[tr][tc] = __builtin_amdgcn_mfma_f32_16x16x32_bf16(
                            a0[tr], bh[tc], acc[tr][tc], 0, 0, 0);
            }
            const int kbn = (kbe + 2) & 7;
#pragma unroll
            for (int tr = 0; tr < 2; ++tr)
                a0[tr] = *(const bf16x8*)&ehi[((size_t)(g0 + tr) * 8 + kbn) * 512 + lane * 8];
            {
                bf16x8 bh[4];
#pragma unroll
                for (int tc = 0; tc < 4; ++tc)
                    bh[tc] = *(const bf16x8*)&Bsh[(tc * 8 + kbo) * 512 + lane * 8];
#pragma unroll
                for (int tr = 0; tr < 2; ++tr)
#pragma unroll
                    for (int tc = 0; tc < 4; ++tc)
                        acc[tr][tc] = __builtin_amdgcn_mfma_f32_16x16x32_bf16(
                            a1[tr], bh[tc], acc[tr][tc], 0, 0, 0);
            }
        }

        if ((unsigned)(jb - i_base) < 128u)
            mine_tile<true>(acc, sqjc, lblc, enc, lbl_i_s, pmax, nmin, i_base, jb, wrow, q, lx);
        else
            mine_tile<false>(acc, sqjc, lblc, enc, lbl_i_s, pmax, nmin, i_base, jb, wrow, q, lx);
    }

    // once-per-kernel cross-lane reduce (16-lane groups) + spread-address atomics
#pragma unroll
    for (int r = 0; r < 8; ++r) {
        unsigned pm = pmax[r], nm = nmin[r];
#pragma unroll
        for (int mm = 1; mm < 16; mm <<= 1) {
            const unsigned pm2 = __shfl_xor(pm, mm, 64);
            const unsigned nm2 = __shfl_xor(nm, mm, 64);
            pm = pm >= pm2 ? pm : pm2;
            nm = nm <= nm2 ? nm : nm2;
        }
        if (lx == r) {
            const int row = i_base + wrow + (r >> 2) * 16 + q * 4 + (r & 3);
            atomicMax(&pos_key[row], pm);
            atomicMin(&neg_key[row], nm);
        }
    }
}

// ---- finalize: decode keys, exact fp32 gather, hinge, per-block partials; the ticket's
//      last block performs the (order-identical) final reduction in-kernel.
__global__ __launch_bounds__(256) void final_k(
        const float* __restrict__ emb,
        const unsigned int* __restrict__ pos_key, const unsigned int* __restrict__ neg_key,
        float* __restrict__ pbsum, float* __restrict__ pbcnt,
        unsigned int* __restrict__ ticket, float* __restrict__ out) {
    __shared__ float ssum[4], scnt[4];
    __shared__ float fs[4], fc[4];
    __shared__ unsigned int lastf;
    const int tid = threadIdx.x;
    const int w = tid >> 6;
    const int lane = tid & 63;
    const int i = blockIdx.x * 4 + w;

    const unsigned pk = pos_key[i], nk = neg_key[i];
    const int pi = 8191 - (int)(pk & 8191u);
    const int ni = 8191 - (int)(nk & 8191u);
    const bool valid = (pk != 0u) && (nk != 0xFFFFFFFFu);

    const float4 av  = *reinterpret_cast<const float4*>(&emb[(size_t)i  * ND + lane * 4]);
    const float4 pvv = *reinterpret_cast<const float4*>(&emb[(size_t)pi * ND + lane * 4]);
    const float4 nvv = *reinterpret_cast<const float4*>(&emb[(size_t)ni * ND + lane * 4]);
    float sap, san;
    {
        const float d0 = av.x - pvv.x + EPS_F, d1 = av.y - pvv.y + EPS_F;
        const float d2 = av.z - pvv.z + EPS_F, d3 = av.w - pvv.w + EPS_F;
        sap = d0 * d0 + d1 * d1 + d2 * d2 + d3 * d3;
        const float e0 = av.x - nvv.x + EPS_F, e1 = av.y - nvv.y + EPS_F;
        const float e2 = av.z - nvv.z + EPS_F, e3 = av.w - nvv.w + EPS_F;
        san = e0 * e0 + e1 * e1 + e2 * e2 + e3 * e3;
    }
#pragma unroll
    for (int m = 32; m; m >>= 1) {
        sap += __shfl_down(sap, m, 64);
        san += __shfl_down(san, m, 64);
    }
    if (lane == 0) {
        const float per = fmaxf(sqrtf(sap) - sqrtf(san) + MARGIN_F, 0.0f);
        ssum[w] = valid ? per : 0.0f;
        scnt[w] = valid ? 1.0f : 0.0f;
    }
    __syncthreads();
    if (tid == 0) {
        pbsum[blockIdx.x] = ssum[0] + ssum[1] + ssum[2] + ssum[3];
        pbcnt[blockIdx.x] = scnt[0] + scnt[1] + scnt[2] + scnt[3];
        __threadfence();                               // partials visible device-wide
        lastf = (atomicAdd(ticket, 1u) == (unsigned)(NFIN - 1)) ? 1u : 0u;
    }
    __syncthreads();
    if (lastf != 0u) {                                 // uniform per block
        float s = 0.0f, c = 0.0f;
#pragma unroll
        for (int r = 0; r < NFIN / 256; ++r) {         // atomic-RMW reads: device-coherent
            s += atomicAdd(&pbsum[r * 256 + tid], 0.0f);
            c += atomicAdd(&pbcnt[r * 256 + tid], 0.0f);
        }
#pragma unroll
        for (int m = 32; m; m >>= 1) { s += __shfl_down(s, m, 64); c += __shfl_down(c, m, 64); }
        if (lane == 0) { fs[w] = s; fc[w] = c; }
        __syncthreads();
        if (tid == 0) {
            const float S = fs[0] + fs[1] + fs[2] + fs[3];
            const float C = fc[0] + fc[1] + fc[2] + fc[3];
            out[0] = (C > 0.0f) ? (S / fmaxf(C, 1.0f)) : 0.0f;
        }
    }
}

extern "C" void kernel_launch(void* const* d_in, const int* in_sizes, int n_in,
                              void* d_out, int out_size, void* d_ws, size_t ws_size,
                              hipStream_t stream) {
    const float* emb = (const float*)d_in[0];
    const int* labels = (const int*)d_in[1];
    float* out = (float*)d_out;

    char* ws = (char*)d_ws;
    unsigned short* ehi = (unsigned short*)ws;                         // 4 MB packed
    float* sqnb = (float*)(ws + (size_t)NB * ND * 2);                  // 32 KB
    unsigned int* pos_key = (unsigned int*)(sqnb + NB);                // 32 KB
    unsigned int* neg_key = pos_key + NB;                              // 32 KB
    float* pbsum = (float*)(neg_key + NB);                             // 8 KB
    float* pbcnt = pbsum + NFIN;                                       // 8 KB
    unsigned int* ticket = (unsigned int*)(pbcnt + NFIN);              // 4 B

    hipLaunchKernelGGL(prep_k, dim3(NB / 16), dim3(512), 0, stream,
                       emb, ehi, sqnb, pos_key, neg_key, ticket);
    hipLaunchKernelGGL(pair_k, dim3(1024), dim3(256), 0, stream,
                       ehi, sqnb, labels, pos_key, neg_key);
    hipLaunchKernelGGL(final_k, dim3(NFIN), dim3(256), 0, stream,
                       emb, pos_key, neg_key, pbsum, pbcnt, ticket, out);
}

// Round 7
// 116.472 us; speedup vs baseline: 10.5584x; 1.3630x over previous
//
#include <hip/hip_runtime.h>
#include <math.h>

#define NB 8192
#define ND 256
#define MARGIN_F 0.3f
#define EPS_F 1e-6f
#define BIAS_F 512.0f          // v = |e_j|^2 + BIAS - 2*dot stays strictly positive -> u = -v/2 < 0
#define NFIN 2048              // finalize grid

typedef __attribute__((ext_vector_type(8))) short bf16x8;
typedef __attribute__((ext_vector_type(4))) float f32x4;

__device__ __forceinline__ unsigned short f2bf(float x) {
    unsigned int u = __float_as_uint(x);
    return (unsigned short)((u + 0x7fffu + ((u >> 16) & 1u)) >> 16);
}

__device__ __forceinline__ void gld16(const void* g, void* l) {
    __builtin_amdgcn_global_load_lds(
        (const __attribute__((address_space(1))) void*)g,
        (__attribute__((address_space(3))) void*)l, 16, 0, 0);
}

// ---- prep: fp32 -> bf16 packed in MFMA-fragment order, + biased sq norms, + key init ----
// Packed layout: subtile = (row>>4)*8 + (k>>5); within: lane = ((k>>3)&3)*16 + (row&15), 8 bf16.
__global__ __launch_bounds__(512) void prep_k(const float* __restrict__ emb,
                                              unsigned short* __restrict__ ehi,
                                              float* __restrict__ sqnb,
                                              unsigned int* __restrict__ pos_key,
                                              unsigned int* __restrict__ neg_key) {
    __shared__ float sm[8][16];
    const int tid = threadIdx.x;
    const int tk = tid >> 6;          // k-tile 0..7
    const int lane = tid & 63;
    const int q = lane >> 4;
    const int lx = lane & 15;
    const int row = blockIdx.x * 16 + lx;
    const int k = tk * 32 + q * 8;

    const float4 v0 = *reinterpret_cast<const float4*>(&emb[(size_t)row * ND + k]);
    const float4 v1 = *reinterpret_cast<const float4*>(&emb[(size_t)row * ND + k + 4]);
    ushort4 h0, h1;
    h0.x = f2bf(v0.x); h0.y = f2bf(v0.y); h0.z = f2bf(v0.z); h0.w = f2bf(v0.w);
    h1.x = f2bf(v1.x); h1.y = f2bf(v1.y); h1.z = f2bf(v1.z); h1.w = f2bf(v1.w);
    *reinterpret_cast<ushort4*>(&ehi[(size_t)blockIdx.x * 4096 + tid * 8])     = h0;
    *reinterpret_cast<ushort4*>(&ehi[(size_t)blockIdx.x * 4096 + tid * 8 + 4]) = h1;

    if (tid >= 32 && tid < 48) pos_key[blockIdx.x * 16 + (tid - 32)] = 0u;
    if (tid >= 48 && tid < 64) neg_key[blockIdx.x * 16 + (tid - 48)] = 0xFFFFFFFFu;

    float s = v0.x * v0.x + v0.y * v0.y + v0.z * v0.z + v0.w * v0.w
            + v1.x * v1.x + v1.y * v1.y + v1.z * v1.z + v1.w * v1.w;
    s += __shfl_xor(s, 16, 64);
    s += __shfl_xor(s, 32, 64);
    if (q == 0) sm[tk][lx] = s;
    __syncthreads();
    if (tid < 16) {
        float t = 0.0f;
#pragma unroll
        for (int wv = 0; wv < 8; ++wv) t += sm[wv][tid];
        sqnb[blockIdx.x * 16 + tid] = t + BIAS_F;
    }
}

// ---- mining on u-keys: acc holds u = dot - 0.5*(|e_j|^2+BIAS) < 0. Larger pairwise v
//      <=> more-negative u <=> larger unsigned bit pattern. pos = float-MIN tree (init/excl
//      +inf), neg = float-MAX tree (init/excl -inf) -> fuse to v_min3/v_max3_f32.
//      Tie-break via enc in low 13 mantissa bits: identical direction to the v0 kernel.
template <bool DIAG>
__device__ __forceinline__ void mine_tile(
        const f32x4 (&acc)[2][4], const int (&lblc)[4], const unsigned (&enc)[4],
        const int* __restrict__ lbl_i_s,
        float (&pkey)[8], float (&nkey)[8],
        int i_base, int jb, int wrow, int q, int lx) {
    const float PINF = __uint_as_float(0x7F800000u);
    const float NINF = __uint_as_float(0xFF800000u);
#pragma unroll
    for (int tr = 0; tr < 2; ++tr) {
#pragma unroll
        for (int reg = 0; reg < 4; ++reg) {
            const int r = tr * 4 + reg;
            const int rowb = wrow + tr * 16 + q * 4 + reg;
            const int lab = lbl_i_s[rowb];
            float pk[4], nk[4];
#pragma unroll
            for (int tc = 0; tc < 4; ++tc) {
                const float keyf = __uint_as_float(
                    (__float_as_uint(acc[tr][tc][reg]) & 0xFFFFE000u) | enc[tc]);
                const bool same = (lblc[tc] == lab);
                bool pc = same;
                if (DIAG) pc = same && ((jb + tc * 16 + lx) != (i_base + rowb));
                pk[tc] = pc ? keyf : PINF;
                nk[tc] = same ? NINF : keyf;
            }
            const float t0 = fminf(fminf(pk[0], pk[1]), pk[2]);
            pkey[r] = fminf(fminf(t0, pk[3]), pkey[r]);
            const float t1 = fmaxf(fmaxf(nk[0], nk[1]), nk[2]);
            nkey[r] = fmaxf(fmaxf(t1, nk[3]), nkey[r]);
        }
    }
}

// ---- MFMA pairwise + hardest mining, v8:
//      v0 tile mapping (4 waves, wave = 32 rows x 64 cols/j-step, acc[2][4] = 32 AGPR).
//      Staging: 16 KB chunks (64 cols x 128 k), fixed buffers B0=k-low / B1=k-high,
//      always staged one phase ahead so gld16 latency hides under 32 MFMAs.
//      A-frags pre-issued per phase BEFORE any gld16 -> their waits never drain staging.
//      acc init = -0.5*sqnb[j]: MFMA produces the mining value directly (no fmaf pass).
//      Regs ~110 < 128 -> true 4 blocks/CU. grid 1024 = 64 i-tiles x 16 slices.
__global__ __launch_bounds__(256, 4) void pair_k(
        const unsigned short* __restrict__ ehi, const float* __restrict__ sqnb,
        const int* __restrict__ labels,
        unsigned int* __restrict__ pos_key, unsigned int* __restrict__ neg_key) {
    __shared__ __align__(16) short Bsh[2][8192];   // 2 x 16 KB chunks
    __shared__ int lbl_i_s[128];

    const int tid = threadIdx.x;
    const int w = tid >> 6;
    const int lane = tid & 63;
    const int q = lane >> 4;
    const int lx = lane & 15;
    const int bid = blockIdx.x;
    const int slice = bid & 15;
    const int i_base = (bid >> 4) * 128;
    const int wrow = w * 32;
    const int g0 = (i_base >> 4) + w * 2;   // A row-group base for this wave (2 subtiles)

    if (tid < 128) lbl_i_s[tid] = labels[i_base + tid];

// stage chunk (j-step JT, k-half KH) -> Bsh[BUF]: 4 col-groups x 4 subtiles, 4 gld16/thread
#define STAGE(JT, KH, BUF)                                                            \
    do {                                                                              \
        _Pragma("unroll")                                                             \
        for (int p = 0; p < 4; ++p)                                                   \
            gld16(ehi + (size_t)((slice * 32 + (JT) * 4 + p) * 8 + (KH) * 4) * 512    \
                      + tid * 8,                                                      \
                  &Bsh[BUF][(p * 256 + tid) * 8]);                                    \
    } while (0)

// A fragment (16B) for row-group g0+TR, k-subtile KB from L2-hot packed ehi
#define AFRAG(TR, KB)                                                                 \
    (*reinterpret_cast<const bf16x8*>(                                                \
        &ehi[((size_t)(g0 + (TR)) * 8 + (KB)) * 512 + lane * 8]))

    STAGE(0, 0, 0);   // prologue: (jt0, k-low) in flight

    float pkey[8], nkey[8];
    const float PINF = __uint_as_float(0x7F800000u);
    const float NINF = __uint_as_float(0xFF800000u);
#pragma unroll
    for (int r = 0; r < 8; ++r) { pkey[r] = PINF; nkey[r] = NINF; }

    __syncthreads();   // prologue gld16 drained; lbl_i_s visible

#pragma unroll 1
    for (int jt = 0; jt < 8; ++jt) {
        const int jb = slice * 512 + jt * 64;

        // ---- phase A: pre-issue A-frags (kb 0..3) + metadata on a clean vm queue ----
        bf16x8 aA[4][2];
#pragma unroll
        for (int kb = 0; kb < 4; ++kb)
#pragma unroll
            for (int tr = 0; tr < 2; ++tr) aA[kb][tr] = AFRAG(tr, kb);

        int lblc[4]; unsigned enc[4]; float sqjc[4];
#pragma unroll
        for (int tc = 0; tc < 4; ++tc) {
            const int jj = jb + tc * 16 + lx;
            lblc[tc] = labels[jj];
            sqjc[tc] = sqnb[jj];
            enc[tc] = 8191u - (unsigned)jj;
        }

        STAGE(jt, 1, 1);   // k-high chunk in flight; hidden under phase-A MFMAs

        f32x4 acc[2][4];   // init = -0.5*sqj: acc ends as u = dot - v/2 (always < 0)
#pragma unroll
        for (int tc = 0; tc < 4; ++tc) {
            const float s0 = -0.5f * sqjc[tc];
#pragma unroll
            for (int tr = 0; tr < 2; ++tr) acc[tr][tc] = (f32x4){s0, s0, s0, s0};
        }

        __builtin_amdgcn_s_setprio(1);
#pragma unroll
        for (int kb = 0; kb < 4; ++kb) {
#pragma unroll
            for (int tc = 0; tc < 4; ++tc) {
                const bf16x8 bh = *reinterpret_cast<const bf16x8*>(
                    &Bsh[0][(tc * 4 + kb) * 512 + lane * 8]);
#pragma unroll
                for (int tr = 0; tr < 2; ++tr)
                    acc[tr][tc] = __builtin_amdgcn_mfma_f32_16x16x32_bf16(
                        aA[kb][tr], bh, acc[tr][tc], 0, 0, 0);
            }
        }
        __builtin_amdgcn_s_setprio(0);
        __syncthreads();   // B1 (k-high) staged+visible; B0 consumed by all waves

        // ---- phase B: pre-issue A-frags (kb 4..7), then next j-step's k-low chunk ----
        bf16x8 aB[4][2];
#pragma unroll
        for (int kb = 0; kb < 4; ++kb)
#pragma unroll
            for (int tr = 0; tr < 2; ++tr) aB[kb][tr] = AFRAG(tr, kb + 4);

        if (jt < 7) STAGE(jt + 1, 0, 0);

        __builtin_amdgcn_s_setprio(1);
#pragma unroll
        for (int kb = 0; kb < 4; ++kb) {
#pragma unroll
            for (int tc = 0; tc < 4; ++tc) {
                const bf16x8 bh = *reinterpret_cast<const bf16x8*>(
                    &Bsh[1][(tc * 4 + kb) * 512 + lane * 8]);
#pragma unroll
                for (int tr = 0; tr < 2; ++tr)
                    acc[tr][tc] = __builtin_amdgcn_mfma_f32_16x16x32_bf16(
                        aB[kb][tr], bh, acc[tr][tc], 0, 0, 0);
            }
        }
        __builtin_amdgcn_s_setprio(0);

        if ((unsigned)(jb - i_base) < 128u)
            mine_tile<true>(acc, lblc, enc, lbl_i_s, pkey, nkey, i_base, jb, wrow, q, lx);
        else
            mine_tile<false>(acc, lblc, enc, lbl_i_s, pkey, nkey, i_base, jb, wrow, q, lx);

        __syncthreads();   // B0 (next k-low) staged+visible; B1 consumed by all waves
    }
#undef STAGE
#undef AFRAG

    // once-per-kernel cross-lane reduce (16-lane groups) + spread-address atomics.
    // Map sentinels back to v0's init values so final_k's validity checks are unchanged.
#pragma unroll
    for (int r = 0; r < 8; ++r) {
        float pm = pkey[r], nm = nkey[r];
#pragma unroll
        for (int mm = 1; mm < 16; mm <<= 1) {
            pm = fminf(pm, __shfl_xor(pm, mm, 64));
            nm = fmaxf(nm, __shfl_xor(nm, mm, 64));
        }
        if (lx == r) {
            const int row = i_base + wrow + (r >> 2) * 16 + q * 4 + (r & 3);
            const unsigned pmb = (pm == PINF) ? 0u : __float_as_uint(pm);
            const unsigned nmb = (nm == NINF) ? 0xFFFFFFFFu : __float_as_uint(nm);
            atomicMax(&pos_key[row], pmb);   // more-negative u => larger bits => hardest pos
            atomicMin(&neg_key[row], nmb);   // least-negative u => smaller bits => hardest neg
        }
    }
}

// ---- finalize: decode keys, exact fp32 gather, hinge, per-block partial stores ----
__global__ __launch_bounds__(256) void final_k(
        const float* __restrict__ emb,
        const unsigned int* __restrict__ pos_key, const unsigned int* __restrict__ neg_key,
        float* __restrict__ pbsum, float* __restrict__ pbcnt) {
    __shared__ float ssum[4], scnt[4];
    const int w = threadIdx.x >> 6;
    const int lane = threadIdx.x & 63;
    const int i = blockIdx.x * 4 + w;

    const unsigned pk = pos_key[i], nk = neg_key[i];
    const int pi = 8191 - (int)(pk & 8191u);
    const int ni = 8191 - (int)(nk & 8191u);
    const bool valid = (pk != 0u) && (nk != 0xFFFFFFFFu);

    const float4 av  = *reinterpret_cast<const float4*>(&emb[(size_t)i  * ND + lane * 4]);
    const float4 pvv = *reinterpret_cast<const float4*>(&emb[(size_t)pi * ND + lane * 4]);
    const float4 nvv = *reinterpret_cast<const float4*>(&emb[(size_t)ni * ND + lane * 4]);
    float sap, san;
    {
        const float d0 = av.x - pvv.x + EPS_F, d1 = av.y - pvv.y + EPS_F;
        const float d2 = av.z - pvv.z + EPS_F, d3 = av.w - pvv.w + EPS_F;
        sap = d0 * d0 + d1 * d1 + d2 * d2 + d3 * d3;
        const float e0 = av.x - nvv.x + EPS_F, e1 = av.y - nvv.y + EPS_F;
        const float e2 = av.z - nvv.z + EPS_F, e3 = av.w - nvv.w + EPS_F;
        san = e0 * e0 + e1 * e1 + e2 * e2 + e3 * e3;
    }
#pragma unroll
    for (int m = 32; m; m >>= 1) {
        sap += __shfl_down(sap, m, 64);
        san += __shfl_down(san, m, 64);
    }
    if (lane == 0) {
        const float per = fmaxf(sqrtf(sap) - sqrtf(san) + MARGIN_F, 0.0f);
        ssum[w] = valid ? per : 0.0f;
        scnt[w] = valid ? 1.0f : 0.0f;
    }
    __syncthreads();
    if (threadIdx.x == 0) {
        pbsum[blockIdx.x] = ssum[0] + ssum[1] + ssum[2] + ssum[3];
        pbcnt[blockIdx.x] = scnt[0] + scnt[1] + scnt[2] + scnt[3];
    }
}

// ---- final mean over 2048 per-block partials ----
__global__ __launch_bounds__(256) void reduce_k(const float* __restrict__ pbsum,
                                                const float* __restrict__ pbcnt,
                                                float* __restrict__ out) {
    __shared__ float fs[4], fc[4];
    const int tid = threadIdx.x;
    float s = 0.0f, c = 0.0f;
#pragma unroll
    for (int r = 0; r < NFIN / 256; ++r) {
        s += pbsum[r * 256 + tid];
        c += pbcnt[r * 256 + tid];
    }
#pragma unroll
    for (int m = 32; m; m >>= 1) { s += __shfl_down(s, m, 64); c += __shfl_down(c, m, 64); }
    const int wv = tid >> 6, lane = tid & 63;
    if (lane == 0) { fs[wv] = s; fc[wv] = c; }
    __syncthreads();
    if (tid == 0) {
        const float S = fs[0] + fs[1] + fs[2] + fs[3];
        const float C = fc[0] + fc[1] + fc[2] + fc[3];
        out[0] = (C > 0.0f) ? (S / fmaxf(C, 1.0f)) : 0.0f;
    }
}

extern "C" void kernel_launch(void* const* d_in, const int* in_sizes, int n_in,
                              void* d_out, int out_size, void* d_ws, size_t ws_size,
                              hipStream_t stream) {
    const float* emb = (const float*)d_in[0];
    const int* labels = (const int*)d_in[1];
    float* out = (float*)d_out;

    char* ws = (char*)d_ws;
    unsigned short* ehi = (unsigned short*)ws;                         // 4 MB packed
    float* sqnb = (float*)(ws + (size_t)NB * ND * 2);                  // 32 KB
    unsigned int* pos_key = (unsigned int*)(sqnb + NB);                // 32 KB
    unsigned int* neg_key = pos_key + NB;                              // 32 KB
    float* pbsum = (float*)(neg_key + NB);                             // 8 KB
    float* pbcnt = pbsum + NFIN;                                       // 8 KB

    hipLaunchKernelGGL(prep_k, dim3(NB / 16), dim3(512), 0, stream,
                       emb, ehi, sqnb, pos_key, neg_key);
    hipLaunchKernelGGL(pair_k, dim3(1024), dim3(256), 0, stream,
                       ehi, sqnb, labels, pos_key, neg_key);
    hipLaunchKernelGGL(final_k, dim3(NFIN), dim3(256), 0, stream,
                       emb, pos_key, neg_key, pbsum, pbcnt);
    hipLaunchKernelGGL(reduce_k, dim3(1), dim3(256), 0, stream, pbsum, pbcnt, out);
}

// Round 8
// 115.029 us; speedup vs baseline: 10.6908x; 1.0125x over previous
//
#include <hip/hip_runtime.h>
#include <math.h>

#define NB 8192
#define ND 256
#define MARGIN_F 0.3f
#define EPS_F 1e-6f
#define BIAS_F 512.0f          // v = |e_j|^2 + BIAS - 2*dot > 0  ->  u = -v/2 < 0
#define NFIN 2048              // finalize grid

typedef __attribute__((ext_vector_type(8))) short bf16x8;
typedef __attribute__((ext_vector_type(4))) float f32x4;

__device__ __forceinline__ unsigned short f2bf(float x) {
    unsigned int u = __float_as_uint(x);
    return (unsigned short)((u + 0x7fffu + ((u >> 16) & 1u)) >> 16);
}

__device__ __forceinline__ void gld16(const void* g, void* l) {
    __builtin_amdgcn_global_load_lds(
        (const __attribute__((address_space(1))) void*)g,
        (__attribute__((address_space(3))) void*)l, 16, 0, 0);
}

// ---- prep: fp32 -> bf16 packed in MFMA-fragment order, + biased sq norms, + key init ----
// Packed layout: subtile = (row>>4)*8 + (k>>5); within: lane = ((k>>3)&3)*16 + (row&15), 8 bf16.
__global__ __launch_bounds__(512) void prep_k(const float* __restrict__ emb,
                                              unsigned short* __restrict__ ehi,
                                              float* __restrict__ sqnb,
                                              unsigned int* __restrict__ pos_key,
                                              unsigned int* __restrict__ neg_key) {
    __shared__ float sm[8][16];
    const int tid = threadIdx.x;
    const int tk = tid >> 6;          // k-tile 0..7
    const int lane = tid & 63;
    const int q = lane >> 4;
    const int lx = lane & 15;
    const int row = blockIdx.x * 16 + lx;
    const int k = tk * 32 + q * 8;

    const float4 v0 = *reinterpret_cast<const float4*>(&emb[(size_t)row * ND + k]);
    const float4 v1 = *reinterpret_cast<const float4*>(&emb[(size_t)row * ND + k + 4]);
    ushort4 h0, h1;
    h0.x = f2bf(v0.x); h0.y = f2bf(v0.y); h0.z = f2bf(v0.z); h0.w = f2bf(v0.w);
    h1.x = f2bf(v1.x); h1.y = f2bf(v1.y); h1.z = f2bf(v1.z); h1.w = f2bf(v1.w);
    *reinterpret_cast<ushort4*>(&ehi[(size_t)blockIdx.x * 4096 + tid * 8])     = h0;
    *reinterpret_cast<ushort4*>(&ehi[(size_t)blockIdx.x * 4096 + tid * 8 + 4]) = h1;

    if (tid >= 32 && tid < 48) pos_key[blockIdx.x * 16 + (tid - 32)] = 0u;
    if (tid >= 48 && tid < 64) neg_key[blockIdx.x * 16 + (tid - 48)] = 0xFFFFFFFFu;

    float s = v0.x * v0.x + v0.y * v0.y + v0.z * v0.z + v0.w * v0.w
            + v1.x * v1.x + v1.y * v1.y + v1.z * v1.z + v1.w * v1.w;
    s += __shfl_xor(s, 16, 64);
    s += __shfl_xor(s, 32, 64);
    if (q == 0) sm[tk][lx] = s;
    __syncthreads();
    if (tid < 16) {
        float t = 0.0f;
#pragma unroll
        for (int wv = 0; wv < 8; ++wv) t += sm[wv][tid];
        sqnb[blockIdx.x * 16 + tid] = t + BIAS_F;
    }
}

// ---- mining on u-keys: acc holds u = dot - 0.5*(|e_j|^2+BIAS) < 0 directly (no fmaf).
//      Larger pairwise dist <=> more-negative u. pos = float-MIN tree (excl/init +inf),
//      neg = float-MAX tree (excl/init -inf) -> fuses to v_min3/v_max3_f32.
//      Tie-break enc in low 13 mantissa bits: identical direction to the v0 kernel
//      (more-negative float = larger unsigned bits = larger enc = smaller j on ties).
template <bool DIAG>
__device__ __forceinline__ void mine_tile(
        const f32x4 (&acc)[2][4], const int (&lblc)[4], const unsigned (&enc)[4],
        const int* __restrict__ lbl_i_s,
        float (&pkey)[8], float (&nkey)[8],
        int i_base, int jb, int wrow, int q, int lx) {
    const float PINF = __uint_as_float(0x7F800000u);
    const float NINF = __uint_as_float(0xFF800000u);
#pragma unroll
    for (int tr = 0; tr < 2; ++tr) {
#pragma unroll
        for (int reg = 0; reg < 4; ++reg) {
            const int r = tr * 4 + reg;
            const int rowb = wrow + tr * 16 + q * 4 + reg;
            const int lab = lbl_i_s[rowb];
            float pk[4], nk[4];
#pragma unroll
            for (int tc = 0; tc < 4; ++tc) {
                const float keyf = __uint_as_float(
                    (__float_as_uint(acc[tr][tc][reg]) & 0xFFFFE000u) | enc[tc]);
                const bool same = (lblc[tc] == lab);
                bool pc = same;
                if (DIAG) pc = same && ((jb + tc * 16 + lx) != (i_base + rowb));
                pk[tc] = pc ? keyf : PINF;
                nk[tc] = same ? NINF : keyf;
            }
            const float t0 = fminf(fminf(pk[0], pk[1]), pk[2]);
            pkey[r] = fminf(fminf(t0, pk[3]), pkey[r]);
            const float t1 = fmaxf(fmaxf(nk[0], nk[1]), nk[2]);
            nkey[r] = fmaxf(fmaxf(t1, nk[3]), nkey[r]);
        }
    }
}

// ---- MFMA pairwise + hardest mining: v0 structure verbatim (proven fastest):
//      128x64 j-steps, B-step (32 KB) in LDS, A frags transient from global
//      (a0/a1 double-buffer), 2 barriers/jt, NO setprio. grid 1024 -> 4 blocks/CU.
//      Only change vs v0: acc init = -0.5*sqnb[j] so acc ends as the mining value u,
//      and the mining epilogue uses fused float min3/max3 trees (v8-validated).
__global__ __launch_bounds__(256, 4) void pair_k(
        const unsigned short* __restrict__ ehi, const float* __restrict__ sqnb,
        const int* __restrict__ labels,
        unsigned int* __restrict__ pos_key, unsigned int* __restrict__ neg_key) {
    __shared__ short Bsh[32 * 512];  // B j-step: 64 cols x 256 k = 16384 shorts = 32 KB
    __shared__ int   lbl_i_s[128];

    const int tid = threadIdx.x;
    const int w = tid >> 6;
    const int lane = tid & 63;
    const int q = lane >> 4;
    const int lx = lane & 15;
    const int bid = blockIdx.x;
    const int slice = bid & 15;
    const int i_base = (bid >> 4) * 128;
    const int wrow = w * 32;
    const int g0 = (i_base >> 4) + w * 2;   // A row-group base for this wave (2 subtiles)

    if (tid < 128) lbl_i_s[tid] = labels[i_base + tid];

    float pkey[8], nkey[8];
    const float PINF = __uint_as_float(0x7F800000u);
    const float NINF = __uint_as_float(0xFF800000u);
#pragma unroll
    for (int r = 0; r < 8; ++r) { pkey[r] = PINF; nkey[r] = NINF; }

#pragma unroll 1
    for (int jt = 0; jt < 8; ++jt) {
        const int jb = slice * 512 + jt * 64;
        __syncthreads();   // prev j-step's Bsh reads complete
        // stage B j-step: contiguous 32 KB of packed ehi (8 gld16/thread)
        {
            const unsigned short* srcB = ehi + (size_t)(jb >> 4) * 4096;
#pragma unroll
            for (int p = 0; p < 8; ++p)
                gld16(srcB + ((size_t)p * 256 + tid) * 8, Bsh + (p * 256 + tid) * 8);
        }
        // j-step metadata + first A frags issued before the drain barrier
        int lblc[4]; float sqjc[4]; unsigned enc[4];
#pragma unroll
        for (int tc = 0; tc < 4; ++tc) {
            const int jj = jb + tc * 16 + lx;
            lblc[tc] = labels[jj];
            sqjc[tc] = sqnb[jj];
            enc[tc] = 8191u - (unsigned)jj;
        }
        bf16x8 a0[2], a1[2];
#pragma unroll
        for (int tr = 0; tr < 2; ++tr)
            a0[tr] = *(const bf16x8*)&ehi[((size_t)(g0 + tr) * 8 + 0) * 512 + lane * 8];
        __syncthreads();   // gld16 drained; Bsh visible

        f32x4 acc[2][4];   // init = -0.5*sqj: acc ends as u = dot - v/2 (always < 0)
#pragma unroll
        for (int tc = 0; tc < 4; ++tc) {
            const float s0 = -0.5f * sqjc[tc];
#pragma unroll
            for (int tr = 0; tr < 2; ++tr) acc[tr][tc] = (f32x4){s0, s0, s0, s0};
        }

#pragma unroll 1
        for (int kb2 = 0; kb2 < 4; ++kb2) {
            const int kbe = kb2 * 2, kbo = kbe + 1;
#pragma unroll
            for (int tr = 0; tr < 2; ++tr)
                a1[tr] = *(const bf16x8*)&ehi[((size_t)(g0 + tr) * 8 + kbo) * 512 + lane * 8];
            {
                bf16x8 bh[4];
#pragma unroll
                for (int tc = 0; tc < 4; ++tc)
                    bh[tc] = *(const bf16x8*)&Bsh[(tc * 8 + kbe) * 512 + lane * 8];
#pragma unroll
                for (int tr = 0; tr < 2; ++tr)
#pragma unroll
                    for (int tc = 0; tc < 4; ++tc)
                        acc[tr][tc] = __builtin_amdgcn_mfma_f32_16x16x32_bf16(
                            a0[tr], bh[tc], acc[tr][tc], 0, 0, 0);
            }
            const int kbn = (kbe + 2) & 7;
#pragma unroll
            for (int tr = 0; tr < 2; ++tr)
                a0[tr] = *(const bf16x8*)&ehi[((size_t)(g0 + tr) * 8 + kbn) * 512 + lane * 8];
            {
                bf16x8 bh[4];
#pragma unroll
                for (int tc = 0; tc < 4; ++tc)
                    bh[tc] = *(const bf16x8*)&Bsh[(tc * 8 + kbo) * 512 + lane * 8];
#pragma unroll
                for (int tr = 0; tr < 2; ++tr)
#pragma unroll
                    for (int tc = 0; tc < 4; ++tc)
                        acc[tr][tc] = __builtin_amdgcn_mfma_f32_16x16x32_bf16(
                            a1[tr], bh[tc], acc[tr][tc], 0, 0, 0);
            }
        }

        if ((unsigned)(jb - i_base) < 128u)
            mine_tile<true>(acc, lblc, enc, lbl_i_s, pkey, nkey, i_base, jb, wrow, q, lx);
        else
            mine_tile<false>(acc, lblc, enc, lbl_i_s, pkey, nkey, i_base, jb, wrow, q, lx);
    }

    // once-per-kernel cross-lane reduce (16-lane groups) + spread-address atomics.
    // Map sentinels back to v0's init values so final_k's validity checks are unchanged.
#pragma unroll
    for (int r = 0; r < 8; ++r) {
        float pm = pkey[r], nm = nkey[r];
#pragma unroll
        for (int mm = 1; mm < 16; mm <<= 1) {
            pm = fminf(pm, __shfl_xor(pm, mm, 64));
            nm = fmaxf(nm, __shfl_xor(nm, mm, 64));
        }
        if (lx == r) {
            const int row = i_base + wrow + (r >> 2) * 16 + q * 4 + (r & 3);
            const unsigned pmb = (pm == PINF) ? 0u : __float_as_uint(pm);
            const unsigned nmb = (nm == NINF) ? 0xFFFFFFFFu : __float_as_uint(nm);
            atomicMax(&pos_key[row], pmb);   // more-negative u => larger bits => hardest pos
            atomicMin(&neg_key[row], nmb);   // least-negative u => smaller bits => hardest neg
        }
    }
}

// ---- finalize: decode keys, exact fp32 gather, hinge, per-block partial stores ----
__global__ __launch_bounds__(256) void final_k(
        const float* __restrict__ emb,
        const unsigned int* __restrict__ pos_key, const unsigned int* __restrict__ neg_key,
        float* __restrict__ pbsum, float* __restrict__ pbcnt) {
    __shared__ float ssum[4], scnt[4];
    const int w = threadIdx.x >> 6;
    const int lane = threadIdx.x & 63;
    const int i = blockIdx.x * 4 + w;

    const unsigned pk = pos_key[i], nk = neg_key[i];
    const int pi = 8191 - (int)(pk & 8191u);
    const int ni = 8191 - (int)(nk & 8191u);
    const bool valid = (pk != 0u) && (nk != 0xFFFFFFFFu);

    const float4 av  = *reinterpret_cast<const float4*>(&emb[(size_t)i  * ND + lane * 4]);
    const float4 pvv = *reinterpret_cast<const float4*>(&emb[(size_t)pi * ND + lane * 4]);
    const float4 nvv = *reinterpret_cast<const float4*>(&emb[(size_t)ni * ND + lane * 4]);
    float sap, san;
    {
        const float d0 = av.x - pvv.x + EPS_F, d1 = av.y - pvv.y + EPS_F;
        const float d2 = av.z - pvv.z + EPS_F, d3 = av.w - pvv.w + EPS_F;
        sap = d0 * d0 + d1 * d1 + d2 * d2 + d3 * d3;
        const float e0 = av.x - nvv.x + EPS_F, e1 = av.y - nvv.y + EPS_F;
        const float e2 = av.z - nvv.z + EPS_F, e3 = av.w - nvv.w + EPS_F;
        san = e0 * e0 + e1 * e1 + e2 * e2 + e3 * e3;
    }
#pragma unroll
    for (int m = 32; m; m >>= 1) {
        sap += __shfl_down(sap, m, 64);
        san += __shfl_down(san, m, 64);
    }
    if (lane == 0) {
        const float per = fmaxf(sqrtf(sap) - sqrtf(san) + MARGIN_F, 0.0f);
        ssum[w] = valid ? per : 0.0f;
        scnt[w] = valid ? 1.0f : 0.0f;
    }
    __syncthreads();
    if (threadIdx.x == 0) {
        pbsum[blockIdx.x] = ssum[0] + ssum[1] + ssum[2] + ssum[3];
        pbcnt[blockIdx.x] = scnt[0] + scnt[1] + scnt[2] + scnt[3];
    }
}

// ---- final mean over 2048 per-block partials ----
__global__ __launch_bounds__(256) void reduce_k(const float* __restrict__ pbsum,
                                                const float* __restrict__ pbcnt,
                                                float* __restrict__ out) {
    __shared__ float fs[4], fc[4];
    const int tid = threadIdx.x;
    float s = 0.0f, c = 0.0f;
#pragma unroll
    for (int r = 0; r < NFIN / 256; ++r) {
        s += pbsum[r * 256 + tid];
        c += pbcnt[r * 256 + tid];
    }
#pragma unroll
    for (int m = 32; m; m >>= 1) { s += __shfl_down(s, m, 64); c += __shfl_down(c, m, 64); }
    const int wv = tid >> 6, lane = tid & 63;
    if (lane == 0) { fs[wv] = s; fc[wv] = c; }
    __syncthreads();
    if (tid == 0) {
        const float S = fs[0] + fs[1] + fs[2] + fs[3];
        const float C = fc[0] + fc[1] + fc[2] + fc[3];
        out[0] = (C > 0.0f) ? (S / fmaxf(C, 1.0f)) : 0.0f;
    }
}

extern "C" void kernel_launch(void* const* d_in, const int* in_sizes, int n_in,
                              void* d_out, int out_size, void* d_ws, size_t ws_size,
                              hipStream_t stream) {
    const float* emb = (const float*)d_in[0];
    const int* labels = (const int*)d_in[1];
    float* out = (float*)d_out;

    char* ws = (char*)d_ws;
    unsigned short* ehi = (unsigned short*)ws;                         // 4 MB packed
    float* sqnb = (float*)(ws + (size_t)NB * ND * 2);                  // 32 KB
    unsigned int* pos_key = (unsigned int*)(sqnb + NB);                // 32 KB
    unsigned int* neg_key = pos_key + NB;                              // 32 KB
    float* pbsum = (float*)(neg_key + NB);                             // 8 KB
    float* pbcnt = pbsum + NFIN;                                       // 8 KB

    hipLaunchKernelGGL(prep_k, dim3(NB / 16), dim3(512), 0, stream,
                       emb, ehi, sqnb, pos_key, neg_key);
    hipLaunchKernelGGL(pair_k, dim3(1024), dim3(256), 0, stream,
                       ehi, sqnb, labels, pos_key, neg_key);
    hipLaunchKernelGGL(final_k, dim3(NFIN), dim3(256), 0, stream,
                       emb, pos_key, neg_key, pbsum, pbcnt);
    hipLaunchKernelGGL(reduce_k, dim3(1), dim3(256), 0, stream, pbsum, pbcnt, out);
}